// Round 6
// baseline (375.760 us; speedup 1.0000x reference)
//
#include <hip/hip_runtime.h>
#include <cstdint>

// Problem constants (from reference setup_inputs): B=256, IN=1024, OUT=1024.
#define BATCH 256
#define INF   1024
#define OUTF  1024

typedef float floatx4 __attribute__((ext_vector_type(4)));  // native vec for nontemporal

// ---------------------------------------------------------------------------
// Decode pulses [n][32] (floats 0./1., index 0 = MSB) -> f32 values [n].
// Coalesced: each thread reads its own contiguous 128 B (8x float4) and
// writes one float (256 B per wave, contiguous). Used for BOTH x and w —
// w stays row-major [o][k]; the GEMM reads it as per-lane float4 rows.
// ---------------------------------------------------------------------------
__device__ __forceinline__ uint32_t assemble_bits(const float4* __restrict__ p4) {
    uint32_t u = 0;
#pragma unroll
    for (int j = 0; j < 8; ++j) {
        float4 v = p4[j];
        int sh = 31 - j * 4;  // pulse index j*4 -> bit (31 - j*4)
        u |= (v.x > 0.5f ? 1u : 0u) << sh;
        u |= (v.y > 0.5f ? 1u : 0u) << (sh - 1);
        u |= (v.z > 0.5f ? 1u : 0u) << (sh - 2);
        u |= (v.w > 0.5f ? 1u : 0u) << (sh - 3);
    }
    return u;
}

__global__ __launch_bounds__(256) void decode_pulses(
    const float* __restrict__ pulses, float* __restrict__ out, int n) {
    int i = blockIdx.x * blockDim.x + threadIdx.x;
    if (i >= n) return;
    const float4* p4 = reinterpret_cast<const float4*>(pulses) + (size_t)i * 8;
    out[i] = __uint_as_float(assemble_bits(p4));
}

// ---------------------------------------------------------------------------
// GEMM with strict left-to-right FP32 accumulation + pulse re-encode.
// Block (64,4): o = bx*64+tx (lane-contiguous in w rows), each thread owns
// TWO batch rows (BQ=2) sharing every w float4 load -> L2 w-traffic halves.
// w is [o][k]: each lane streams its own row as float4 (128 B line fully
// consumed by one thread over 8 consecutive steps -> L1-friendly).
// fp contract(off): hipcc defaults to -ffp-contract=fast-honor-pragmas; a
// fused v_fmac skips product rounding and breaks bit-exactness vs the
// reference's round(mul) -> round(add) sequence.
// ---------------------------------------------------------------------------
__global__ __launch_bounds__(256) void gemm_encode(
    const float* __restrict__ xf,   // [BATCH][INF]
    const float* __restrict__ wf,   // [OUTF][INF]  (row-major, NOT transposed)
    float* __restrict__ out)        // [BATCH][OUTF][32]
{
#pragma clang fp contract(off)
    const int o  = blockIdx.x * 64 + threadIdx.x;
    const int b0 = (blockIdx.y * 4 + threadIdx.y) * 2;   // two consecutive rows

    const float4* __restrict__ w4 = reinterpret_cast<const float4*>(wf + (size_t)o * INF);
    const float4* __restrict__ xa = reinterpret_cast<const float4*>(xf + (size_t)b0 * INF);
    const float4* __restrict__ xb = reinterpret_cast<const float4*>(xf + (size_t)(b0 + 1) * INF);

    float acc0 = 0.0f, acc1 = 0.0f;
#pragma unroll 4
    for (int kk = 0; kk < INF / 4; ++kk) {
        float4 w = w4[kk];      // per-lane own row, 16 B
        float4 a = xa[kk];      // wave-uniform broadcast
        float4 b = xb[kk];
        // strictly ascending k within each independent output chain
        acc0 = acc0 + a.x * w.x;
        acc0 = acc0 + a.y * w.y;
        acc0 = acc0 + a.z * w.z;
        acc0 = acc0 + a.w * w.w;
        acc1 = acc1 + b.x * w.x;
        acc1 = acc1 + b.y * w.y;
        acc1 = acc1 + b.z * w.z;
        acc1 = acc1 + b.w * w.w;
    }

    // Re-encode both results to pulse bits; non-temporal stores keep the
    // 32 MB streaming output from evicting the hot 4 MB w set in L2.
    float accs[2] = {acc0, acc1};
#pragma unroll
    for (int q = 0; q < 2; ++q) {
        uint32_t u = __float_as_uint(accs[q]);
        floatx4* dst = reinterpret_cast<floatx4*>(
            reinterpret_cast<float*>(out) + ((size_t)(b0 + q) * OUTF + o) * 32);
#pragma unroll
        for (int j = 0; j < 8; ++j) {
            int sh = 31 - j * 4;
            floatx4 v = { (float)((u >> sh) & 1u),
                          (float)((u >> (sh - 1)) & 1u),
                          (float)((u >> (sh - 2)) & 1u),
                          (float)((u >> (sh - 3)) & 1u) };
            __builtin_nontemporal_store(v, dst + j);
        }
    }
}

extern "C" void kernel_launch(void* const* d_in, const int* in_sizes, int n_in,
                              void* d_out, int out_size, void* d_ws, size_t ws_size,
                              hipStream_t stream) {
    const float* x_pulses = (const float*)d_in[0];   // [256][1024][32]
    const float* w_pulses = (const float*)d_in[1];   // [1024][1024][32]
    float* out = (float*)d_out;                      // [256][1024][32]

    float* xf = (float*)d_ws;                        // 256*1024 floats  (1 MB)
    float* wf = xf + (size_t)BATCH * INF;            // 1024*1024 floats (4 MB)

    // 1) decode x -> xf [B][IN]
    {
        int n = BATCH * INF;                         // 262144
        decode_pulses<<<(n + 255) / 256, 256, 0, stream>>>(x_pulses, xf, n);
    }
    // 2) decode w -> wf [OUT][IN] (row-major, no transpose)
    {
        int n = OUTF * INF;                          // 1048576
        decode_pulses<<<n / 256, 256, 0, stream>>>(w_pulses, wf, n);
    }
    // 3) GEMM + encode (BQ=2 batches per thread)
    {
        dim3 grid(OUTF / 64, BATCH / 8);             // (16, 32)
        dim3 block(64, 4);
        gemm_encode<<<grid, block, 0, stream>>>(xf, wf, out);
    }
}

// Round 9
// 279.793 us; speedup vs baseline: 1.3430x; 1.3430x over previous
//
#include <hip/hip_runtime.h>
#include <cstdint>

// Problem constants (from reference setup_inputs): B=256, IN=1024, OUT=1024.
#define BATCH 256
#define INF   1024
#define OUTF  1024

// ---------------------------------------------------------------------------
// Decode helper: 32 pulse floats (index 0 = MSB) -> uint32 bit pattern.
// p4 points at the value's 8 contiguous float4s (128 B).
// ---------------------------------------------------------------------------
__device__ __forceinline__ uint32_t assemble_bits(const float4* __restrict__ p4) {
    uint32_t u = 0;
#pragma unroll
    for (int j = 0; j < 8; ++j) {
        float4 v = p4[j];
        int sh = 31 - j * 4;  // pulse index j*4 -> bit (31 - j*4)
        u |= (v.x > 0.5f ? 1u : 0u) << sh;
        u |= (v.y > 0.5f ? 1u : 0u) << (sh - 1);
        u |= (v.z > 0.5f ? 1u : 0u) << (sh - 2);
        u |= (v.w > 0.5f ? 1u : 0u) << (sh - 3);
    }
    return u;
}

// Simple decode (used for x): thread i reads its own 128 B, writes 1 float.
__global__ __launch_bounds__(256) void decode_pulses(
    const float* __restrict__ pulses, float* __restrict__ out, int n) {
    int i = blockIdx.x * blockDim.x + threadIdx.x;
    if (i >= n) return;
    const float4* p4 = reinterpret_cast<const float4*>(pulses) + (size_t)i * 8;
    out[i] = __uint_as_float(assemble_bits(p4));
}

// ---------------------------------------------------------------------------
// Decode w pulses [OUT][IN][32] -> TRANSPOSED wT[IN][OUT], via LDS tile so
// both the 128 MB pulse read and the 4 MB wT write are coalesced.
// Block: 512 threads, tile = 64 o x 64 k. grid (o-tiles=16, k-tiles=16).
// ---------------------------------------------------------------------------
__global__ __launch_bounds__(512) void decode_w_transpose(
    const float* __restrict__ pulses,   // [OUTF][INF][32]
    float* __restrict__ wT)             // [INF][OUTF]
{
    __shared__ float tile[64][65];      // [o][k], +1 pad: transpose-read free
    const int o0 = blockIdx.x * 64;
    const int k0 = blockIdx.y * 64;
    const int t  = threadIdx.x;         // 0..511

    // decode: thread handles o = t/8, k = (t&7) + 8j  (8 values, 2 KB read)
    const int o_loc  = t >> 3;
    const int k_base = t & 7;
    const float4* src = reinterpret_cast<const float4*>(pulses)
                        + ((size_t)(o0 + o_loc) * INF + k0 + k_base) * 8;
#pragma unroll
    for (int j = 0; j < 8; ++j) {
        tile[o_loc][k_base + 8 * j] = __uint_as_float(assemble_bits(src + (size_t)(8 * j) * 8));
    }
    __syncthreads();

    // write out: lane-contiguous in o (256 B per wave-store).
    const int col = t & 63;             // o offset
    const int w   = t >> 6;             // 0..7
#pragma unroll
    for (int j2 = 0; j2 < 8; ++j2) {
        int krow = j2 * 8 + w;
        wT[(size_t)(k0 + krow) * OUTF + o0 + col] = tile[col][krow];
    }
}

// ---------------------------------------------------------------------------
// GEMM with strict left-to-right FP32 accumulation + pulse re-encode.
// Block (64,4) = 256 threads, covers 64 o x 8 b (BQ=2 per thread).
// Per K-tile (KT=64): stage w_s[64k][64o] (FULL 16 KB: 4 float4/thread,
// k-rows wrow, +16, +32, +48) + x_s[8][64], then compute from LDS:
//   w_s[k][tx]  -> bank = lane&31 (2-way, free)
//   x_s[row][k] -> uniform-address float4 broadcast (free)
// w global traffic: 512 blocks x 16 KB x 16 tiles = 128 MB (vs 1 GB unstaged).
// fp contract(off): a fused v_fmac skips product rounding and breaks
// bit-exactness vs the reference's round(mul) -> round(add) sequence.
// ---------------------------------------------------------------------------
__global__ __launch_bounds__(256) void gemm_encode(
    const float* __restrict__ xf,   // [BATCH][INF]
    const float* __restrict__ wT,   // [INF][OUTF]
    float* __restrict__ out)        // [BATCH][OUTF][32]
{
#pragma clang fp contract(off)
    __shared__ float w_s[64 * 64];      // [k][o] linear, 16 KB
    __shared__ float x_s[8][64];        // [b][k], 2 KB (reads are uniform bcast)
    const int tx = threadIdx.x, ty = threadIdx.y;
    const int t  = ty * 64 + tx;        // 0..255
    const int o0 = blockIdx.x * 64;
    const int b0 = blockIdx.y * 8;

    const int wrow = t >> 4;            // 0..15 (base k row)
    const int wseg = t & 15;            // 16 B segment within the 64-o row

    float acc0 = 0.0f, acc1 = 0.0f;

    for (int kt = 0; kt < 16; ++kt) {
        const int k0 = kt * 64;
        __syncthreads();   // previous tile's compute done before overwrite
        // stage w tile: 4 float4 chunks per thread -> full 64x64 (16 KB)
        {
#pragma unroll
            for (int h = 0; h < 4; ++h) {
                float4 v = *reinterpret_cast<const float4*>(
                    wT + (size_t)(k0 + wrow + 16 * h) * OUTF + o0 + wseg * 4);
                *reinterpret_cast<float4*>(&w_s[(size_t)(t + 256 * h) * 4]) = v;
            }
        }
        // stage x tile: 8 rows x 64 k, first 128 threads (waves 0-1)
        if (t < 128) {
            int xr = t >> 4, xs = t & 15;
            float4 v = *reinterpret_cast<const float4*>(
                xf + (size_t)(b0 + xr) * INF + k0 + xs * 4);
            *reinterpret_cast<float4*>(&x_s[xr][xs * 4]) = v;
        }
        __syncthreads();

        const float* wcol  = w_s + tx;
        const float* xrow0 = x_s[ty * 2];
        const float* xrow1 = x_s[ty * 2 + 1];
#pragma unroll
        for (int k4 = 0; k4 < 16; ++k4) {
            float4 xa = *reinterpret_cast<const float4*>(xrow0 + k4 * 4);
            float4 xb = *reinterpret_cast<const float4*>(xrow1 + k4 * 4);
            float w0 = wcol[(k4 * 4 + 0) * 64];
            float w1 = wcol[(k4 * 4 + 1) * 64];
            float w2 = wcol[(k4 * 4 + 2) * 64];
            float w3 = wcol[(k4 * 4 + 3) * 64];
            // strictly ascending k within each independent output chain
            acc0 = acc0 + xa.x * w0;
            acc0 = acc0 + xa.y * w1;
            acc0 = acc0 + xa.z * w2;
            acc0 = acc0 + xa.w * w3;
            acc1 = acc1 + xb.x * w0;
            acc1 = acc1 + xb.y * w1;
            acc1 = acc1 + xb.z * w2;
            acc1 = acc1 + xb.w * w3;
        }
    }

    // Re-encode both results to pulse bits (plain cached stores: L2 merges
    // the 16 B partials into full lines -> exactly 32 MB HBM writes).
    const int o = o0 + tx;
    float accs[2] = {acc0, acc1};
#pragma unroll
    for (int q = 0; q < 2; ++q) {
        uint32_t u = __float_as_uint(accs[q]);
        float4* dst = reinterpret_cast<float4*>(out)
                      + ((size_t)(b0 + ty * 2 + q) * OUTF + o) * 8;
#pragma unroll
        for (int j = 0; j < 8; ++j) {
            int sh = 31 - j * 4;
            dst[j] = make_float4((float)((u >> sh) & 1u),
                                 (float)((u >> (sh - 1)) & 1u),
                                 (float)((u >> (sh - 2)) & 1u),
                                 (float)((u >> (sh - 3)) & 1u));
        }
    }
}

extern "C" void kernel_launch(void* const* d_in, const int* in_sizes, int n_in,
                              void* d_out, int out_size, void* d_ws, size_t ws_size,
                              hipStream_t stream) {
    const float* x_pulses = (const float*)d_in[0];   // [256][1024][32]
    const float* w_pulses = (const float*)d_in[1];   // [1024][1024][32]
    float* out = (float*)d_out;                      // [256][1024][32]

    float* xf = (float*)d_ws;                        // 256*1024 floats  (1 MB)
    float* wT = xf + (size_t)BATCH * INF;            // 1024*1024 floats (4 MB)

    // 1) decode x -> xf [B][IN]
    {
        int n = BATCH * INF;                         // 262144
        decode_pulses<<<(n + 255) / 256, 256, 0, stream>>>(x_pulses, xf, n);
    }
    // 2) decode w -> wT [IN][OUT] via LDS-tiled transpose
    {
        decode_w_transpose<<<dim3(16, 16), 512, 0, stream>>>(w_pulses, wT);
    }
    // 3) GEMM + encode (LDS-staged, BQ=2 batches per thread)
    {
        dim3 grid(OUTF / 64, BATCH / 8);             // (16, 32)
        dim3 block(64, 4);
        gemm_encode<<<grid, block, 0, stream>>>(xf, wT, out);
    }
}

// Round 14
// 251.671 us; speedup vs baseline: 1.4931x; 1.1117x over previous
//
#include <hip/hip_runtime.h>
#include <cstdint>

// Problem constants (from reference setup_inputs): B=256, IN=1024, OUT=1024.
#define BATCH 256
#define INF   1024
#define OUTF  1024

// ---------------------------------------------------------------------------
// Decode helper: 32 pulse floats (index 0 = MSB) -> uint32 bit pattern.
// p4 points at the value's 8 contiguous float4s (128 B).
// ---------------------------------------------------------------------------
__device__ __forceinline__ uint32_t assemble_bits(const float4* __restrict__ p4) {
    uint32_t u = 0;
#pragma unroll
    for (int j = 0; j < 8; ++j) {
        float4 v = p4[j];
        int sh = 31 - j * 4;  // pulse index j*4 -> bit (31 - j*4)
        u |= (v.x > 0.5f ? 1u : 0u) << sh;
        u |= (v.y > 0.5f ? 1u : 0u) << (sh - 1);
        u |= (v.z > 0.5f ? 1u : 0u) << (sh - 2);
        u |= (v.w > 0.5f ? 1u : 0u) << (sh - 3);
    }
    return u;
}

// Streaming decode (x AND w): thread i reads its own 128 B, writes 1 float.
// Output keeps the input's row-major layout (no transpose kernel needed;
// gemm_encode transposes w during LDS staging).
__global__ __launch_bounds__(256) void decode_pulses(
    const float* __restrict__ pulses, float* __restrict__ out, int n) {
    int i = blockIdx.x * blockDim.x + threadIdx.x;
    if (i >= n) return;
    const float4* p4 = reinterpret_cast<const float4*>(pulses) + (size_t)i * 8;
    out[i] = __uint_as_float(assemble_bits(p4));
}

// ---------------------------------------------------------------------------
// GEMM with strict left-to-right FP32 accumulation + pulse re-encode.
// Block (64,4) = 256 threads, covers 64 o x 8 b (BQ=2 per thread).
// Register double-buffer: tile t+1's global loads are issued BEFORE tile t's
// compute, hiding L2 latency under the 256-VALU compute phase; the reg->LDS
// writes land between the two barriers. w is staged with an in-LDS transpose:
// per-thread float4 along k from wf[o][k] -> 4x ds_write_b32 into w_s[k][o]
// (banks = o%32 -> 2-way = free). Compute reads:
//   w_s[k][tx]  -> bank = lane&31 (2-way, free)
//   x_s[row][k] -> uniform-address float4 broadcast (free)
// fp contract(off): a fused v_fmac skips product rounding and breaks
// bit-exactness vs the reference's round(mul) -> round(add) sequence.
// ---------------------------------------------------------------------------
__global__ __launch_bounds__(256) void gemm_encode(
    const float* __restrict__ xf,   // [BATCH][INF]
    const float* __restrict__ wf,   // [OUTF][INF] (row-major decoded)
    float* __restrict__ out)        // [BATCH][OUTF][32]
{
#pragma clang fp contract(off)
    __shared__ float w_s[64 * 64];      // [k][o] linear, 16 KB
    __shared__ float x_s[8][64];        // [b][k], 2 KB (reads are uniform bcast)
    const int tx = threadIdx.x, ty = threadIdx.y;
    const int t  = ty * 64 + tx;        // 0..255
    const int o0 = blockIdx.x * 64;
    const int b0 = blockIdx.y * 8;

    // w staging role: o-row = t&63, k-segment base = t>>6 (segments s, s+4, s+8, s+12)
    const int o_loc = t & 63;
    const int seg0  = t >> 6;           // 0..3
    const float* __restrict__ wbase = wf + (size_t)(o0 + o_loc) * INF;
    // x staging role (threads 0..127): row = t>>4, 16 B segment = t&15
    const int xr = t >> 4, xs = t & 15;

    float4 wreg[4];
    float4 xreg;

    // ---- prologue: stage tile 0 ----
#pragma unroll
    for (int h = 0; h < 4; ++h)
        wreg[h] = *reinterpret_cast<const float4*>(wbase + (seg0 + 4 * h) * 4);
    if (t < 128)
        xreg = *reinterpret_cast<const float4*>(xf + (size_t)(b0 + xr) * INF + xs * 4);
#pragma unroll
    for (int h = 0; h < 4; ++h) {
        const int s = seg0 + 4 * h;
        w_s[(s * 4 + 0) * 64 + o_loc] = wreg[h].x;
        w_s[(s * 4 + 1) * 64 + o_loc] = wreg[h].y;
        w_s[(s * 4 + 2) * 64 + o_loc] = wreg[h].z;
        w_s[(s * 4 + 3) * 64 + o_loc] = wreg[h].w;
    }
    if (t < 128)
        *reinterpret_cast<float4*>(&x_s[xr][xs * 4]) = xreg;
    __syncthreads();

    float acc0 = 0.0f, acc1 = 0.0f;

    for (int kt = 0; kt < 16; ++kt) {
        // ---- prefetch tile kt+1 into registers (latency hides under compute) ----
        if (kt < 15) {
            const int k0 = (kt + 1) * 64;
#pragma unroll
            for (int h = 0; h < 4; ++h)
                wreg[h] = *reinterpret_cast<const float4*>(wbase + k0 + (seg0 + 4 * h) * 4);
            if (t < 128)
                xreg = *reinterpret_cast<const float4*>(xf + (size_t)(b0 + xr) * INF + k0 + xs * 4);
        }

        // ---- compute tile kt from LDS ----
        const float* wcol  = w_s + tx;
        const float* xrow0 = x_s[ty * 2];
        const float* xrow1 = x_s[ty * 2 + 1];
#pragma unroll
        for (int k4 = 0; k4 < 16; ++k4) {
            float4 xa = *reinterpret_cast<const float4*>(xrow0 + k4 * 4);
            float4 xb = *reinterpret_cast<const float4*>(xrow1 + k4 * 4);
            float w0 = wcol[(k4 * 4 + 0) * 64];
            float w1 = wcol[(k4 * 4 + 1) * 64];
            float w2 = wcol[(k4 * 4 + 2) * 64];
            float w3 = wcol[(k4 * 4 + 3) * 64];
            // strictly ascending k within each independent output chain
            acc0 = acc0 + xa.x * w0;
            acc0 = acc0 + xa.y * w1;
            acc0 = acc0 + xa.z * w2;
            acc0 = acc0 + xa.w * w3;
            acc1 = acc1 + xb.x * w0;
            acc1 = acc1 + xb.y * w1;
            acc1 = acc1 + xb.z * w2;
            acc1 = acc1 + xb.w * w3;
        }
        __syncthreads();   // all compute on tile kt done before overwrite

        // ---- write prefetched tile kt+1 to LDS ----
        if (kt < 15) {
#pragma unroll
            for (int h = 0; h < 4; ++h) {
                const int s = seg0 + 4 * h;
                w_s[(s * 4 + 0) * 64 + o_loc] = wreg[h].x;
                w_s[(s * 4 + 1) * 64 + o_loc] = wreg[h].y;
                w_s[(s * 4 + 2) * 64 + o_loc] = wreg[h].z;
                w_s[(s * 4 + 3) * 64 + o_loc] = wreg[h].w;
            }
            if (t < 128)
                *reinterpret_cast<float4*>(&x_s[xr][xs * 4]) = xreg;
            __syncthreads();   // tile kt+1 visible before next compute
        }
    }

    // Re-encode both results to pulse bits (plain cached stores: L2 merges
    // the 16 B partials into full lines -> exactly 32 MB HBM writes).
    const int o = o0 + tx;
    float accs[2] = {acc0, acc1};
#pragma unroll
    for (int q = 0; q < 2; ++q) {
        uint32_t u = __float_as_uint(accs[q]);
        float4* dst = reinterpret_cast<float4*>(out)
                      + ((size_t)(b0 + ty * 2 + q) * OUTF + o) * 8;
#pragma unroll
        for (int j = 0; j < 8; ++j) {
            int sh = 31 - j * 4;
            dst[j] = make_float4((float)((u >> sh) & 1u),
                                 (float)((u >> (sh - 1)) & 1u),
                                 (float)((u >> (sh - 2)) & 1u),
                                 (float)((u >> (sh - 3)) & 1u));
        }
    }
}

extern "C" void kernel_launch(void* const* d_in, const int* in_sizes, int n_in,
                              void* d_out, int out_size, void* d_ws, size_t ws_size,
                              hipStream_t stream) {
    const float* x_pulses = (const float*)d_in[0];   // [256][1024][32]
    const float* w_pulses = (const float*)d_in[1];   // [1024][1024][32]
    float* out = (float*)d_out;                      // [256][1024][32]

    float* xf = (float*)d_ws;                        // 256*1024 floats  (1 MB)
    float* wf = xf + (size_t)BATCH * INF;            // 1024*1024 floats (4 MB)

    // 1) decode x -> xf [B][IN]
    {
        int n = BATCH * INF;                         // 262144
        decode_pulses<<<(n + 255) / 256, 256, 0, stream>>>(x_pulses, xf, n);
    }
    // 2) decode w -> wf [OUT][IN] (row-major streaming, no transpose)
    {
        int n = OUTF * INF;                          // 1048576
        decode_pulses<<<n / 256, 256, 0, stream>>>(w_pulses, wf, n);
    }
    // 3) GEMM + encode (reg-double-buffered LDS staging, BQ=2)
    {
        dim3 grid(OUTF / 64, BATCH / 8);             // (16, 32)
        dim3 block(64, 4);
        gemm_encode<<<grid, block, 0, stream>>>(xf, wf, out);
    }
}